// Round 10
// baseline (117.184 us; speedup 1.0000x reference)
//
#include <hip/hip_runtime.h>
#include <math.h>

#define B  4
#define N  4096
#define C  128
#define K  16
#define NB 3

typedef unsigned int u32;
typedef unsigned long long u64;
typedef __attribute__((ext_vector_type(8))) short short8_t;
typedef __attribute__((ext_vector_type(4))) float f32x4;

__device__ __forceinline__ float leaky(float x) {
  return x >= 0.f ? x : 0.01f * x;
}
__device__ __forceinline__ unsigned short f2bf(float f) {
  u32 x = __float_as_uint(f);
  return (unsigned short)((x + 0x7FFFu + ((x >> 16) & 1u)) >> 16);  // RNE
}
__device__ __forceinline__ float bflo(u32 u) { return __uint_as_float(u << 16); }
__device__ __forceinline__ float bfhi(u32 u) { return __uint_as_float(u & 0xFFFF0000u); }
__device__ __forceinline__ u32 umaxu(u32 a, u32 b) { return a > b ? a : b; }

// XCD-pair swizzle for the fused pipeline (kept from round 7; harmless).
__device__ __forceinline__ void swz_batch(int bidx, int* b, int* rgrp) {
  int q = bidx >> 3, x = bidx & 7;
  *b = x >> 1;
  *rgrp = (q << 1) | (x & 1);
}

// 64-lane max reduce, pure VALU via DPP. Result valid in lane 63.
__device__ __forceinline__ u32 dpp_max64(u32 v) {
  v = umaxu(v, (u32)__builtin_amdgcn_update_dpp(0, (int)v, 0x111, 0xf, 0xf, false));
  v = umaxu(v, (u32)__builtin_amdgcn_update_dpp(0, (int)v, 0x112, 0xf, 0xf, false));
  v = umaxu(v, (u32)__builtin_amdgcn_update_dpp(0, (int)v, 0x114, 0xf, 0xf, false));
  v = umaxu(v, (u32)__builtin_amdgcn_update_dpp(0, (int)v, 0x118, 0xf, 0xf, false));
  v = umaxu(v, (u32)__builtin_amdgcn_update_dpp(0, (int)v, 0x142, 0xa, 0xf, false));
  v = umaxu(v, (u32)__builtin_amdgcn_update_dpp(0, (int)v, 0x143, 0xc, 0xf, false));
  return v;
}

// ---- KNN (faithful: k+1 LARGEST sq-dists, drop first) ----
// 2048 blocks x 512 threads (8 waves). ONE wave per row, 64 candidates/lane.
// Threshold-select: (1) per-lane max tracked in the distance pass; (2) bitonic
// sort of the 64 lane-max keys -> tau = 17th-largest lane-max (guarantees >=17
// survivors); (3) ballot-compaction of candidates with enc >= tau into LDS
// (E[survivors]~20); (4) bitonic sort of survivors; ranks 1..16 are output.
// Occupancy is LDS-capped at 2 blocks/CU (= 4 waves/EU), so pin waves_per_eu
// to exactly 4: gives the register allocator the full 128-VGPR budget so
// denc[64] stays in registers (round 9: compiler chose 64 VGPR + 78MB spill).
__global__ __attribute__((amdgpu_waves_per_eu(4, 4)))
__launch_bounds__(512) void knn_kernel(const float* __restrict__ xyz,
                                       int* __restrict__ idxOut) {
  __shared__ float4 p[N];       // 64 KB
  __shared__ u64 surv[8][64];   // 4 KB survivor buffer, per wave
  int bidx = blockIdx.x;
  int b = bidx >> 9;            // 512 blocks per batch
  int row0 = (bidx & 511) << 3; // 8 rows per block
  const float* src = xyz + b * N * 3;
  int tid = threadIdx.x;

  for (int e = tid; e < N; e += 512) {
    float x = src[3 * e], y = src[3 * e + 1], z = src[3 * e + 2];
    // sq = (x*x + y*y) + z*z, exact f32 rounding, no FMA contraction
    float sq = __fadd_rn(__fadd_rn(__fmul_rn(x, x), __fmul_rn(y, y)), __fmul_rn(z, z));
    p[e] = make_float4(x, y, z, sq);
  }
  __syncthreads();

  int lane = tid & 63;
  int wave = tid >> 6;   // 0..7 = local row
  int i = row0 + wave;   // query point within batch

  float4 pi = p[i];
  float xi = pi.x, yi = pi.y, zi = pi.z, sqi = pi.w;

  // Phase A: distances + per-lane argmax
  u32 denc[64];
  u32 lmax = 0u; int lt = 0;
#pragma unroll
  for (int t = 0; t < 64; ++t) {
    float4 pj = p[lane + (t << 6)];
    // dist = (sq_i + sq_j) - 2*dot  (reference op order, no contraction)
    float dt = __fadd_rn(__fmul_rn(xi, pj.x), __fmul_rn(yi, pj.y));
    dt = __fadd_rn(dt, __fmul_rn(zi, pj.z));
    float dd = __fsub_rn(__fadd_rn(sqi, pj.w), __fmul_rn(2.0f, dt));
    u32 bits = __float_as_uint(dd);
    u32 enc = bits ^ ((u32)(((int)bits) >> 31) | 0x80000000u);  // monotone
    denc[t] = enc;
    if (enc > lmax) { lmax = enc; lt = t; }  // strict > : smallest t on tie
  }

  // Phase B: sort the 64 lane-max keys descending; tau = 17th largest value
  u64 skey = ((u64)lmax << 32) | (u32)(4095 - (lane + (lt << 6)));
#pragma unroll
  for (int k2 = 2; k2 <= 64; k2 <<= 1) {
#pragma unroll
    for (int jj = k2 >> 1; jj > 0; jj >>= 1) {
      u64 ok = __shfl_xor(skey, jj, 64);
      bool keepMax = ((lane & jj) == 0) == ((lane & k2) == 0);
      skey = (keepMax == (ok > skey)) ? ok : skey;
    }
  }
  u64 k16 = __shfl(skey, 16, 64);
  u32 tau = (u32)(k16 >> 32);

  // Phase C: ballot-compact survivors (enc >= tau) into surv[wave][]
  int total = 0;
#pragma unroll
  for (int t = 0; t < 64; ++t) {
    bool pred = (denc[t] >= tau);
    u64 bal = __ballot(pred);
    if (bal != 0ull) {  // wave-uniform skip of empty slots
      int pos = total + (int)__builtin_amdgcn_mbcnt_hi(
                            (u32)(bal >> 32),
                            __builtin_amdgcn_mbcnt_lo((u32)bal, 0u));
      if (pred && pos < 64) {
        surv[wave][pos] = ((u64)denc[t] << 32) | (u32)(4095 - (lane + (t << 6)));
      }
      total += (int)__popcll(bal);
    }
  }

  if (total <= 64) {
    // Phase D: sort survivors descending (zeros pad to the end), emit 1..16.
    u64 sk = (lane < total) ? surv[wave][lane] : 0ull;
#pragma unroll
    for (int k2 = 2; k2 <= 64; k2 <<= 1) {
#pragma unroll
      for (int jj = k2 >> 1; jj > 0; jj >>= 1) {
        u64 ok = __shfl_xor(sk, jj, 64);
        bool keepMax = ((lane & jj) == 0) == ((lane & k2) == 0);
        sk = (keepMax == (ok > sk)) ? ok : sk;
      }
    }
    if (lane >= 1 && lane < 17) {
      idxOut[((long long)(b * N + i)) * K + lane - 1] = 4095 - (int)(u32)sk;
    }
  } else {
    // Fallback (degenerate ties; never on this input): exact iterative
    // extraction, recomputing from LDS so denc[] is never dynamically indexed.
    u32 cmax = lmax; u32 ct = (u32)lt;
    u64 elim = 0ull;
    for (int r = 0; r < 17; ++r) {
      u32 wmax = dpp_max64(cmax);
      u32 s_wmax = (u32)__builtin_amdgcn_readlane((int)wmax, 63);
      u64 mask = __ballot(cmax == s_wmax);
      int s_wj;
      if (__popcll(mask) == 1) {
        int l = (int)(__ffsll((long long)mask) - 1);
        int myj = lane + ((int)ct << 6);
        s_wj = __builtin_amdgcn_readlane(myj, l);
      } else {
        u32 jv = (cmax == s_wmax) ? (u32)(lane + ((int)ct << 6)) : 0xFFFFFFFFu;
#pragma unroll
        for (int off = 1; off < 64; off <<= 1) {
          u32 oj = (u32)__shfl_xor((int)jv, off, 64);
          jv = oj < jv ? oj : jv;
        }
        s_wj = (int)__builtin_amdgcn_readfirstlane((int)jv);
      }
      if (r > 0 && lane == 0)
        idxOut[((long long)(b * N + i)) * K + (r - 1)] = s_wj;
      if (r == 16) break;
      if (lane == (s_wj & 63)) {
        elim |= 1ull << (s_wj >> 6);
        cmax = 0u; ct = 0u;
        for (int t = 0; t < 64; ++t) {  // runtime loop over LDS (no denc use)
          if (elim & (1ull << t)) continue;
          float4 pj = p[lane + (t << 6)];
          float dt2 = __fadd_rn(__fmul_rn(xi, pj.x), __fmul_rn(yi, pj.y));
          dt2 = __fadd_rn(dt2, __fmul_rn(zi, pj.z));
          float dd = __fsub_rn(__fadd_rn(sqi, pj.w), __fmul_rn(2.0f, dt2));
          u32 bits = __float_as_uint(dd);
          u32 enc = bits ^ ((u32)(((int)bits) >> 31) | 0x80000000u);
          if (enc > cmax) { cmax = enc; ct = (u32)t; }
        }
      }
    }
  }
}

// ---- Abf = bf16(leaky(P)) : XCD-pair swizzled ----
__global__ __launch_bounds__(256) void cvtA_kernel(const float* __restrict__ P,
                                                   unsigned short* __restrict__ Abf) {
  int b, rgrp;
  swz_batch(blockIdx.x, &b, &rgrp);
  int tid = threadIdx.x;
  size_t off = ((size_t)b * N + rgrp * 16 + (tid >> 4)) * C + (tid & 15) * 8;
  const float4* p4 = (const float4*)(P + off);
  float4 a = p4[0], c = p4[1];
  unsigned short u0 = f2bf(leaky(a.x)), u1 = f2bf(leaky(a.y));
  unsigned short u2 = f2bf(leaky(a.z)), u3 = f2bf(leaky(a.w));
  unsigned short u4 = f2bf(leaky(c.x)), u5 = f2bf(leaky(c.y));
  unsigned short u6 = f2bf(leaky(c.z)), u7 = f2bf(leaky(c.w));
  uint4 o;
  o.x = (u32)u0 | ((u32)u1 << 16);
  o.y = (u32)u2 | ((u32)u3 << 16);
  o.z = (u32)u4 | ((u32)u5 << 16);
  o.w = (u32)u6 | ((u32)u7 << 16);
  *(uint4*)(Abf + off) = o;
}

// ---- W (f32) -> bf16, all 3 blocks at once ----
__global__ __launch_bounds__(256) void cvtW_kernel(const float* __restrict__ Wc,
                                                   const float* __restrict__ Wg,
                                                   unsigned short* __restrict__ Wbf) {
  int e = blockIdx.x * 256 + threadIdx.x;  // 0..98303
  if (e < NB * C * C) Wbf[e] = f2bf(Wc[e]);
  else Wbf[e] = f2bf(Wg[e - NB * C * C]);
}

// ---- fused per-block-iter: gather-sum (bf16) + dual MFMA matmul + epilogue
__global__ __launch_bounds__(256) void fused_kernel(
    const float* __restrict__ Pcur, const unsigned short* __restrict__ Abf,
    const int* __restrict__ idx,
    const unsigned short* __restrict__ Wcbf, const unsigned short* __restrict__ Wgbf,
    const float* __restrict__ bc, const float* __restrict__ bg,
    float* __restrict__ Pnxt, unsigned short* __restrict__ AbfN) {
  __shared__ int ji[256];
  __shared__ unsigned short Sl[16][136];  // +8 pad: 272B row stride, 16B aligned
  int bb, rgrp;
  swz_batch(blockIdx.x, &bb, &rgrp);
  int row0 = bb * N + rgrp * 16;  // global row
  int tid = threadIdx.x;
  ji[tid] = idx[row0 * K + tid];
  __syncthreads();

  // batch base for neighbor indices (idx entries are within-batch!)
  const unsigned short* AbfB = Abf + ((size_t)bb << 12) * C;

  // gather: thread (r,g) sums 8 cols [g*8, g*8+8) of row r over 16 neighbors
  {
    int r = tid >> 4, g = tid & 15;
    float s0 = 0.f, s1 = 0.f, s2 = 0.f, s3 = 0.f, s4 = 0.f, s5 = 0.f, s6 = 0.f, s7 = 0.f;
#pragma unroll
    for (int t = 0; t < K; ++t) {
      int j = ji[(r << 4) + t];
      uint4 v = *(const uint4*)(AbfB + (size_t)j * C + g * 8);
      s0 += bflo(v.x); s1 += bfhi(v.x);
      s2 += bflo(v.y); s3 += bfhi(v.y);
      s4 += bflo(v.z); s5 += bfhi(v.z);
      s6 += bflo(v.w); s7 += bfhi(v.w);
    }
    uint4 o;
    o.x = (u32)f2bf(s0) | ((u32)f2bf(s1) << 16);
    o.y = (u32)f2bf(s2) | ((u32)f2bf(s3) << 16);
    o.z = (u32)f2bf(s4) | ((u32)f2bf(s5) << 16);
    o.w = (u32)f2bf(s6) | ((u32)f2bf(s7) << 16);
    *(uint4*)(&Sl[r][g * 8]) = o;
  }
  __syncthreads();

  // MFMA: A row = lane&15, k-chunk = (lane>>4)*8 ; B col = lane&15, same k-chunk
  int lane = tid & 63, wave = tid >> 6;
  int lrow = lane & 15;
  int kgrp = (lane >> 4) * 8;
  f32x4 acc0 = {0.f, 0.f, 0.f, 0.f};
  f32x4 acc1 = {0.f, 0.f, 0.f, 0.f};
  int ct0 = wave * 2, ct1 = ct0 + 1;
  const unsigned short* abase = Abf + (size_t)(row0 + lrow) * C + kgrp;
  const unsigned short* wc0 = Wcbf + (size_t)(ct0 * 16 + lrow) * C + kgrp;
  const unsigned short* wc1 = Wcbf + (size_t)(ct1 * 16 + lrow) * C + kgrp;
  const unsigned short* wg0 = Wgbf + (size_t)(ct0 * 16 + lrow) * C + kgrp;
  const unsigned short* wg1 = Wgbf + (size_t)(ct1 * 16 + lrow) * C + kgrp;
#pragma unroll
  for (int ks = 0; ks < 4; ++ks) {
    short8_t a = *(const short8_t*)(abase + ks * 32);
    short8_t b0 = *(const short8_t*)(wc0 + ks * 32);
    short8_t b1 = *(const short8_t*)(wc1 + ks * 32);
    acc0 = __builtin_amdgcn_mfma_f32_16x16x32_bf16(a, b0, acc0, 0, 0, 0);
    acc1 = __builtin_amdgcn_mfma_f32_16x16x32_bf16(a, b1, acc1, 0, 0, 0);
  }
#pragma unroll
  for (int ks = 0; ks < 4; ++ks) {
    short8_t sf = *(const short8_t*)(&Sl[lrow][kgrp + ks * 32]);
    short8_t b0 = *(const short8_t*)(wg0 + ks * 32);
    short8_t b1 = *(const short8_t*)(wg1 + ks * 32);
    acc0 = __builtin_amdgcn_mfma_f32_16x16x32_bf16(sf, b0, acc0, 0, 0, 0);
    acc1 = __builtin_amdgcn_mfma_f32_16x16x32_bf16(sf, b1, acc1, 0, 0, 0);
  }

  // epilogue: D row=(lane>>4)*4+q, col=lane&15 (within 16x16 tile)
#pragma unroll
  for (int side = 0; side < 2; ++side) {
    int col = (side == 0 ? ct0 : ct1) * 16 + lrow;
    float bias = bc[col] + 16.0f * bg[col];
    f32x4 acc = (side == 0) ? acc0 : acc1;
#pragma unroll
    for (int q = 0; q < 4; ++q) {
      int row = row0 + (lane >> 4) * 4 + q;
      float v = (acc[q] + bias) * (1.0f / 17.0f);
      float vn = v + Pcur[(size_t)row * C + col];
      Pnxt[(size_t)row * C + col] = vn;
      if (AbfN) AbfN[(size_t)row * C + col] = f2bf(leaky(vn));
    }
  }
}

extern "C" void kernel_launch(void* const* d_in, const int* in_sizes, int n_in,
                              void* d_out, int out_size, void* d_ws, size_t ws_size,
                              hipStream_t stream) {
  const float* xyz = (const float*)d_in[0];
  const float* pts = (const float*)d_in[1];
  const float* Wc = (const float*)d_in[5];
  const float* bc = (const float*)d_in[6];
  const float* Wg = (const float*)d_in[7];
  const float* bg = (const float*)d_in[8];

  const size_t PE = (size_t)B * N * C;            // 2097152 elements
  const size_t idxB = (size_t)B * N * K * 4;      // 1 MB
  const size_t WbfB = (size_t)2 * NB * C * C * 2; // 192 KB
  char* ws = (char*)d_ws;
  float* Pa            = (float*)ws;                                  // 8 MB
  int* idx             = (int*)(ws + PE * 4);                         // 1 MB
  unsigned short* Abf0 = (unsigned short*)(ws + PE * 4 + idxB);       // 4 MB
  unsigned short* Wbf  = (unsigned short*)(ws + PE * 4 + idxB + PE * 2);
  unsigned short* Abf1 = (unsigned short*)(ws + PE * 4 + idxB + PE * 2 + WbfB);
  unsigned short* Wcbf = Wbf;
  unsigned short* Wgbf = Wbf + (size_t)NB * C * C;
  const size_t need = PE * 4 + idxB + PE * 2 + WbfB + PE * 2;  // 17.2 MB
  const bool fusedAbf = (ws_size >= need);

  hipLaunchKernelGGL(cvtW_kernel, dim3((2 * NB * C * C) / 256), dim3(256), 0, stream,
                     Wc, Wg, Wbf);
  hipLaunchKernelGGL(cvtA_kernel, dim3(1024), dim3(256), 0, stream, pts, Abf0);
  hipLaunchKernelGGL(knn_kernel, dim3(2048), dim3(512), 0, stream, xyz, idx);

  // ping-pong: pts (read-only) -> d_out -> Pa -> d_out
  const float* cur = pts;
  float* nxt = (float*)d_out;
  unsigned short* AbfCur = Abf0;
  unsigned short* AbfNxt = fusedAbf ? Abf1 : Abf0;
  for (int i = 0; i < NB; ++i) {
    if (!fusedAbf && i > 0) {
      hipLaunchKernelGGL(cvtA_kernel, dim3(1024), dim3(256), 0, stream, cur, Abf0);
      AbfCur = Abf0;
    }
    unsigned short* an = (fusedAbf && i < NB - 1) ? AbfNxt : (unsigned short*)nullptr;
    hipLaunchKernelGGL(fused_kernel, dim3(1024), dim3(256), 0, stream,
                       cur, AbfCur, idx, Wcbf + (size_t)i * C * C, Wgbf + (size_t)i * C * C,
                       bc + (size_t)i * C, bg + (size_t)i * C, nxt, an);
    cur = nxt;
    nxt = (i == 0) ? Pa : (float*)d_out;
    if (fusedAbf) { unsigned short* ta = AbfCur; AbfCur = AbfNxt; AbfNxt = ta; }
  }
}

// Round 11
// 110.812 us; speedup vs baseline: 1.0575x; 1.0575x over previous
//
#include <hip/hip_runtime.h>
#include <math.h>

#define B  4
#define N  4096
#define C  128
#define K  16
#define NB 3

typedef unsigned int u32;
typedef unsigned long long u64;
typedef __attribute__((ext_vector_type(8))) short short8_t;
typedef __attribute__((ext_vector_type(4))) float f32x4;

__device__ __forceinline__ float leaky(float x) {
  return x >= 0.f ? x : 0.01f * x;
}
__device__ __forceinline__ unsigned short f2bf(float f) {
  u32 x = __float_as_uint(f);
  return (unsigned short)((x + 0x7FFFu + ((x >> 16) & 1u)) >> 16);  // RNE
}
__device__ __forceinline__ float bflo(u32 u) { return __uint_as_float(u << 16); }
__device__ __forceinline__ float bfhi(u32 u) { return __uint_as_float(u & 0xFFFF0000u); }
__device__ __forceinline__ u32 umaxu(u32 a, u32 b) { return a > b ? a : b; }

// XCD-pair swizzle for the fused pipeline (kept from round 7; harmless).
__device__ __forceinline__ void swz_batch(int bidx, int* b, int* rgrp) {
  int q = bidx >> 3, x = bidx & 7;
  *b = x >> 1;
  *rgrp = (q << 1) | (x & 1);
}

// 64-lane max reduce, pure VALU via DPP. Result valid in lane 63.
__device__ __forceinline__ u32 dpp_max64(u32 v) {
  v = umaxu(v, (u32)__builtin_amdgcn_update_dpp(0, (int)v, 0x111, 0xf, 0xf, false));
  v = umaxu(v, (u32)__builtin_amdgcn_update_dpp(0, (int)v, 0x112, 0xf, 0xf, false));
  v = umaxu(v, (u32)__builtin_amdgcn_update_dpp(0, (int)v, 0x114, 0xf, 0xf, false));
  v = umaxu(v, (u32)__builtin_amdgcn_update_dpp(0, (int)v, 0x118, 0xf, 0xf, false));
  v = umaxu(v, (u32)__builtin_amdgcn_update_dpp(0, (int)v, 0x142, 0xa, 0xf, false));
  v = umaxu(v, (u32)__builtin_amdgcn_update_dpp(0, (int)v, 0x143, 0xc, 0xf, false));
  return v;
}

// exact monotone-encoded squared distance (reference op order, no contraction)
__device__ __forceinline__ u32 encdist(float xi, float yi, float zi, float sqi,
                                       float4 pj) {
  float dt = __fadd_rn(__fmul_rn(xi, pj.x), __fmul_rn(yi, pj.y));
  dt = __fadd_rn(dt, __fmul_rn(zi, pj.z));
  float dd = __fsub_rn(__fadd_rn(sqi, pj.w), __fmul_rn(2.0f, dt));
  u32 bits = __float_as_uint(dd);
  return bits ^ ((u32)(((int)bits) >> 31) | 0x80000000u);
}

// ---- KNN (faithful: k+1 LARGEST sq-dists, drop first) ----
// 2048 blocks x 512 threads (8 waves). ONE wave per row, 64 candidates/lane.
// Register-lean threshold-select (round 9's denc[64] spilled 78MB to scratch;
// attributes couldn't raise the 64-VGPR budget):
//  A: distances; keep only hi-16 of each enc, packed 2/reg (denc16[32]) +
//     EXACT per-lane max (lmax/lt).
//  B: bitonic sort of the 64 exact lane-max keys -> tau = 17th largest.
//  C: predicate hi16(enc) >= hi16(tau) (superset of enc>=tau); ballot-compact;
//     matching lanes RECOMPUTE the exact enc (one LDS read + ~8 VALU, ~17 of
//     64 slots have any survivor) and store the exact u64 key into LDS.
//  D: bitonic sort survivors; ranks 1..16 output (rank 0 = dropped max).
// Key (enc<<32)|(4095-j) == jax top_k order (value desc, index asc).
// Fallback if survivors > 64 (degenerate ties only): exact iterative extract.
__global__ __launch_bounds__(512) void knn_kernel(const float* __restrict__ xyz,
                                                  int* __restrict__ idxOut) {
  __shared__ float4 p[N];       // 64 KB
  __shared__ u64 surv[8][64];   // 4 KB survivor buffer, per wave
  int bidx = blockIdx.x;
  int b = bidx >> 9;            // 512 blocks per batch
  int row0 = (bidx & 511) << 3; // 8 rows per block
  const float* src = xyz + b * N * 3;
  int tid = threadIdx.x;

  for (int e = tid; e < N; e += 512) {
    float x = src[3 * e], y = src[3 * e + 1], z = src[3 * e + 2];
    // sq = (x*x + y*y) + z*z, exact f32 rounding, no FMA contraction
    float sq = __fadd_rn(__fadd_rn(__fmul_rn(x, x), __fmul_rn(y, y)), __fmul_rn(z, z));
    p[e] = make_float4(x, y, z, sq);
  }
  __syncthreads();

  int lane = tid & 63;
  int wave = tid >> 6;   // 0..7 = local row
  int i = row0 + wave;   // query point within batch

  float4 pi = p[i];
  float xi = pi.x, yi = pi.y, zi = pi.z, sqi = pi.w;

  // Phase A: distances; pack hi16; exact per-lane argmax
  u32 denc16[32];
  u32 lmax = 0u; int lt = 0;
#pragma unroll
  for (int t2 = 0; t2 < 32; ++t2) {
    int t0 = t2 * 2, t1 = t0 + 1;
    float4 pj0 = p[lane + (t0 << 6)];
    float4 pj1 = p[lane + (t1 << 6)];
    u32 e0 = encdist(xi, yi, zi, sqi, pj0);
    u32 e1 = encdist(xi, yi, zi, sqi, pj1);
    if (e0 > lmax) { lmax = e0; lt = t0; }  // strict > : smallest t on tie
    if (e1 > lmax) { lmax = e1; lt = t1; }
    denc16[t2] = (e0 >> 16) | (e1 & 0xFFFF0000u);
  }

  // Phase B: sort the 64 exact lane-max keys descending; tau = 17th largest
  u64 skey = ((u64)lmax << 32) | (u32)(4095 - (lane + (lt << 6)));
#pragma unroll
  for (int k2 = 2; k2 <= 64; k2 <<= 1) {
#pragma unroll
    for (int jj = k2 >> 1; jj > 0; jj >>= 1) {
      u64 ok = __shfl_xor(skey, jj, 64);
      bool keepMax = ((lane & jj) == 0) == ((lane & k2) == 0);
      skey = (keepMax == (ok > skey)) ? ok : skey;
    }
  }
  u64 k16 = __shfl(skey, 16, 64);
  u32 tau16 = (u32)(k16 >> 48);  // hi16 of tau

  // Phase C: ballot-compact candidates with hi16(enc) >= tau16; exact-key store
  int total = 0;
#pragma unroll
  for (int t = 0; t < 64; ++t) {
    u32 h = (t & 1) ? (denc16[t >> 1] >> 16) : (denc16[t >> 1] & 0xFFFFu);
    bool pred = (h >= tau16);
    u64 bal = __ballot(pred);
    if (bal != 0ull) {  // wave-uniform skip of empty slots
      int pos = total + (int)__builtin_amdgcn_mbcnt_hi(
                            (u32)(bal >> 32),
                            __builtin_amdgcn_mbcnt_lo((u32)bal, 0u));
      if (pred && pos < 64) {
        u32 enc = encdist(xi, yi, zi, sqi, p[lane + (t << 6)]);  // exact
        surv[wave][pos] = ((u64)enc << 32) | (u32)(4095 - (lane + (t << 6)));
      }
      total += (int)__popcll(bal);
    }
  }

  if (total <= 64) {
    // Phase D: sort survivors descending (zeros pad to the end), emit 1..16.
    u64 sk = (lane < total) ? surv[wave][lane] : 0ull;
#pragma unroll
    for (int k2 = 2; k2 <= 64; k2 <<= 1) {
#pragma unroll
      for (int jj = k2 >> 1; jj > 0; jj >>= 1) {
        u64 ok = __shfl_xor(sk, jj, 64);
        bool keepMax = ((lane & jj) == 0) == ((lane & k2) == 0);
        sk = (keepMax == (ok > sk)) ? ok : sk;
      }
    }
    if (lane >= 1 && lane < 17) {
      idxOut[((long long)(b * N + i)) * K + lane - 1] = 4095 - (int)(u32)sk;
    }
  } else {
    // Fallback (degenerate ties; never on this input): exact iterative
    // extraction, recomputing from LDS (no register array involved).
    u32 cmax = lmax; u32 ct = (u32)lt;
    u64 elim = 0ull;
    for (int r = 0; r < 17; ++r) {
      u32 wmax = dpp_max64(cmax);
      u32 s_wmax = (u32)__builtin_amdgcn_readlane((int)wmax, 63);
      u64 mask = __ballot(cmax == s_wmax);
      int s_wj;
      if (__popcll(mask) == 1) {
        int l = (int)(__ffsll((long long)mask) - 1);
        int myj = lane + ((int)ct << 6);
        s_wj = __builtin_amdgcn_readlane(myj, l);
      } else {
        u32 jv = (cmax == s_wmax) ? (u32)(lane + ((int)ct << 6)) : 0xFFFFFFFFu;
#pragma unroll
        for (int off = 1; off < 64; off <<= 1) {
          u32 oj = (u32)__shfl_xor((int)jv, off, 64);
          jv = oj < jv ? oj : jv;
        }
        s_wj = (int)__builtin_amdgcn_readfirstlane((int)jv);
      }
      if (r > 0 && lane == 0)
        idxOut[((long long)(b * N + i)) * K + (r - 1)] = s_wj;
      if (r == 16) break;
      if (lane == (s_wj & 63)) {
        elim |= 1ull << (s_wj >> 6);
        cmax = 0u; ct = 0u;
        for (int t = 0; t < 64; ++t) {
          if (elim & (1ull << t)) continue;
          u32 enc = encdist(xi, yi, zi, sqi, p[lane + (t << 6)]);
          if (enc > cmax) { cmax = enc; ct = (u32)t; }
        }
      }
    }
  }
}

// ---- Abf = bf16(leaky(P)) : XCD-pair swizzled ----
__global__ __launch_bounds__(256) void cvtA_kernel(const float* __restrict__ P,
                                                   unsigned short* __restrict__ Abf) {
  int b, rgrp;
  swz_batch(blockIdx.x, &b, &rgrp);
  int tid = threadIdx.x;
  size_t off = ((size_t)b * N + rgrp * 16 + (tid >> 4)) * C + (tid & 15) * 8;
  const float4* p4 = (const float4*)(P + off);
  float4 a = p4[0], c = p4[1];
  unsigned short u0 = f2bf(leaky(a.x)), u1 = f2bf(leaky(a.y));
  unsigned short u2 = f2bf(leaky(a.z)), u3 = f2bf(leaky(a.w));
  unsigned short u4 = f2bf(leaky(c.x)), u5 = f2bf(leaky(c.y));
  unsigned short u6 = f2bf(leaky(c.z)), u7 = f2bf(leaky(c.w));
  uint4 o;
  o.x = (u32)u0 | ((u32)u1 << 16);
  o.y = (u32)u2 | ((u32)u3 << 16);
  o.z = (u32)u4 | ((u32)u5 << 16);
  o.w = (u32)u6 | ((u32)u7 << 16);
  *(uint4*)(Abf + off) = o;
}

// ---- W (f32) -> bf16, all 3 blocks at once ----
__global__ __launch_bounds__(256) void cvtW_kernel(const float* __restrict__ Wc,
                                                   const float* __restrict__ Wg,
                                                   unsigned short* __restrict__ Wbf) {
  int e = blockIdx.x * 256 + threadIdx.x;  // 0..98303
  if (e < NB * C * C) Wbf[e] = f2bf(Wc[e]);
  else Wbf[e] = f2bf(Wg[e - NB * C * C]);
}

// ---- fused per-block-iter: gather-sum (bf16) + dual MFMA matmul + epilogue
__global__ __launch_bounds__(256) void fused_kernel(
    const float* __restrict__ Pcur, const unsigned short* __restrict__ Abf,
    const int* __restrict__ idx,
    const unsigned short* __restrict__ Wcbf, const unsigned short* __restrict__ Wgbf,
    const float* __restrict__ bc, const float* __restrict__ bg,
    float* __restrict__ Pnxt, unsigned short* __restrict__ AbfN) {
  __shared__ int ji[256];
  __shared__ unsigned short Sl[16][136];  // +8 pad: 272B row stride, 16B aligned
  int bb, rgrp;
  swz_batch(blockIdx.x, &bb, &rgrp);
  int row0 = bb * N + rgrp * 16;  // global row
  int tid = threadIdx.x;
  ji[tid] = idx[row0 * K + tid];
  __syncthreads();

  // batch base for neighbor indices (idx entries are within-batch!)
  const unsigned short* AbfB = Abf + ((size_t)bb << 12) * C;

  // gather: thread (r,g) sums 8 cols [g*8, g*8+8) of row r over 16 neighbors
  {
    int r = tid >> 4, g = tid & 15;
    float s0 = 0.f, s1 = 0.f, s2 = 0.f, s3 = 0.f, s4 = 0.f, s5 = 0.f, s6 = 0.f, s7 = 0.f;
#pragma unroll
    for (int t = 0; t < K; ++t) {
      int j = ji[(r << 4) + t];
      uint4 v = *(const uint4*)(AbfB + (size_t)j * C + g * 8);
      s0 += bflo(v.x); s1 += bfhi(v.x);
      s2 += bflo(v.y); s3 += bfhi(v.y);
      s4 += bflo(v.z); s5 += bfhi(v.z);
      s6 += bflo(v.w); s7 += bfhi(v.w);
    }
    uint4 o;
    o.x = (u32)f2bf(s0) | ((u32)f2bf(s1) << 16);
    o.y = (u32)f2bf(s2) | ((u32)f2bf(s3) << 16);
    o.z = (u32)f2bf(s4) | ((u32)f2bf(s5) << 16);
    o.w = (u32)f2bf(s6) | ((u32)f2bf(s7) << 16);
    *(uint4*)(&Sl[r][g * 8]) = o;
  }
  __syncthreads();

  // MFMA: A row = lane&15, k-chunk = (lane>>4)*8 ; B col = lane&15, same k-chunk
  int lane = tid & 63, wave = tid >> 6;
  int lrow = lane & 15;
  int kgrp = (lane >> 4) * 8;
  f32x4 acc0 = {0.f, 0.f, 0.f, 0.f};
  f32x4 acc1 = {0.f, 0.f, 0.f, 0.f};
  int ct0 = wave * 2, ct1 = ct0 + 1;
  const unsigned short* abase = Abf + (size_t)(row0 + lrow) * C + kgrp;
  const unsigned short* wc0 = Wcbf + (size_t)(ct0 * 16 + lrow) * C + kgrp;
  const unsigned short* wc1 = Wcbf + (size_t)(ct1 * 16 + lrow) * C + kgrp;
  const unsigned short* wg0 = Wgbf + (size_t)(ct0 * 16 + lrow) * C + kgrp;
  const unsigned short* wg1 = Wgbf + (size_t)(ct1 * 16 + lrow) * C + kgrp;
#pragma unroll
  for (int ks = 0; ks < 4; ++ks) {
    short8_t a = *(const short8_t*)(abase + ks * 32);
    short8_t b0 = *(const short8_t*)(wc0 + ks * 32);
    short8_t b1 = *(const short8_t*)(wc1 + ks * 32);
    acc0 = __builtin_amdgcn_mfma_f32_16x16x32_bf16(a, b0, acc0, 0, 0, 0);
    acc1 = __builtin_amdgcn_mfma_f32_16x16x32_bf16(a, b1, acc1, 0, 0, 0);
  }
#pragma unroll
  for (int ks = 0; ks < 4; ++ks) {
    short8_t sf = *(const short8_t*)(&Sl[lrow][kgrp + ks * 32]);
    short8_t b0 = *(const short8_t*)(wg0 + ks * 32);
    short8_t b1 = *(const short8_t*)(wg1 + ks * 32);
    acc0 = __builtin_amdgcn_mfma_f32_16x16x32_bf16(sf, b0, acc0, 0, 0, 0);
    acc1 = __builtin_amdgcn_mfma_f32_16x16x32_bf16(sf, b1, acc1, 0, 0, 0);
  }

  // epilogue: D row=(lane>>4)*4+q, col=lane&15 (within 16x16 tile)
#pragma unroll
  for (int side = 0; side < 2; ++side) {
    int col = (side == 0 ? ct0 : ct1) * 16 + lrow;
    float bias = bc[col] + 16.0f * bg[col];
    f32x4 acc = (side == 0) ? acc0 : acc1;
#pragma unroll
    for (int q = 0; q < 4; ++q) {
      int row = row0 + (lane >> 4) * 4 + q;
      float v = (acc[q] + bias) * (1.0f / 17.0f);
      float vn = v + Pcur[(size_t)row * C + col];
      Pnxt[(size_t)row * C + col] = vn;
      if (AbfN) AbfN[(size_t)row * C + col] = f2bf(leaky(vn));
    }
  }
}

extern "C" void kernel_launch(void* const* d_in, const int* in_sizes, int n_in,
                              void* d_out, int out_size, void* d_ws, size_t ws_size,
                              hipStream_t stream) {
  const float* xyz = (const float*)d_in[0];
  const float* pts = (const float*)d_in[1];
  const float* Wc = (const float*)d_in[5];
  const float* bc = (const float*)d_in[6];
  const float* Wg = (const float*)d_in[7];
  const float* bg = (const float*)d_in[8];

  const size_t PE = (size_t)B * N * C;            // 2097152 elements
  const size_t idxB = (size_t)B * N * K * 4;      // 1 MB
  const size_t WbfB = (size_t)2 * NB * C * C * 2; // 192 KB
  char* ws = (char*)d_ws;
  float* Pa            = (float*)ws;                                  // 8 MB
  int* idx             = (int*)(ws + PE * 4);                         // 1 MB
  unsigned short* Abf0 = (unsigned short*)(ws + PE * 4 + idxB);       // 4 MB
  unsigned short* Wbf  = (unsigned short*)(ws + PE * 4 + idxB + PE * 2);
  unsigned short* Abf1 = (unsigned short*)(ws + PE * 4 + idxB + PE * 2 + WbfB);
  unsigned short* Wcbf = Wbf;
  unsigned short* Wgbf = Wbf + (size_t)NB * C * C;
  const size_t need = PE * 4 + idxB + PE * 2 + WbfB + PE * 2;  // 17.2 MB
  const bool fusedAbf = (ws_size >= need);

  hipLaunchKernelGGL(cvtW_kernel, dim3((2 * NB * C * C) / 256), dim3(256), 0, stream,
                     Wc, Wg, Wbf);
  hipLaunchKernelGGL(cvtA_kernel, dim3(1024), dim3(256), 0, stream, pts, Abf0);
  hipLaunchKernelGGL(knn_kernel, dim3(2048), dim3(512), 0, stream, xyz, idx);

  // ping-pong: pts (read-only) -> d_out -> Pa -> d_out
  const float* cur = pts;
  float* nxt = (float*)d_out;
  unsigned short* AbfCur = Abf0;
  unsigned short* AbfNxt = fusedAbf ? Abf1 : Abf0;
  for (int i = 0; i < NB; ++i) {
    if (!fusedAbf && i > 0) {
      hipLaunchKernelGGL(cvtA_kernel, dim3(1024), dim3(256), 0, stream, cur, Abf0);
      AbfCur = Abf0;
    }
    unsigned short* an = (fusedAbf && i < NB - 1) ? AbfNxt : (unsigned short*)nullptr;
    hipLaunchKernelGGL(fused_kernel, dim3(1024), dim3(256), 0, stream,
                       cur, AbfCur, idx, Wcbf + (size_t)i * C * C, Wgbf + (size_t)i * C * C,
                       bc + (size_t)i * C, bg + (size_t)i * C, nxt, an);
    cur = nxt;
    nxt = (i == 0) ? Pa : (float*)d_out;
    if (fusedAbf) { unsigned short* ta = AbfCur; AbfCur = AbfNxt; AbfNxt = ta; }
  }
}